// Round 4
// baseline (694.978 us; speedup 1.0000x reference)
//
#include <hip/hip_runtime.h>

// Problem constants (B,C,H,W = 32,512,32,32)
#define B_N   32
#define C_N   512
#define HW_N  1024
#define C8_N  64

typedef short bf16x8 __attribute__((ext_vector_type(8)));
typedef float f32x4  __attribute__((ext_vector_type(4)));

#define LGKM0() asm volatile("s_waitcnt lgkmcnt(0)" ::: "memory")

// round-to-nearest-even fp32 -> bf16 bits (low 16 of result)
static __device__ __forceinline__ unsigned int bf16_bits(float a)
{
    unsigned int u = __float_as_uint(a);
    return (u + 0x7fffu + ((u >> 16) & 1u)) >> 16;
}

// two fp32 -> packed bf16 pair (elem0 low, elem1 high)
static __device__ __forceinline__ unsigned int pack2_bf16(float a, float b)
{
    return bf16_bits(a) | (bf16_bits(b) << 16);
}

// ---------------------------------------------------------------------------
// Kernel 0: transpose + two-term bf16 split of x.
// x[b,c,p] fp32  ->  xt[b,p,c] u32 = (hi<<16)|lo  where x ~= hi + lo (bf16 each)
// xt lives in the att region of d_out (overwritten later by energy_mfma).
// ---------------------------------------------------------------------------
__global__ __launch_bounds__(256) void xsplit_transpose_kernel(
    const float* __restrict__ x, unsigned int* __restrict__ xt)
{
    const int b   = blockIdx.z;
    const int c0  = blockIdx.y * 64;
    const int p0  = blockIdx.x * 64;
    const int tid = threadIdx.x;

    __shared__ unsigned int Ls[64][65];

    const float* xb = x + ((size_t)b * C_N + c0) * HW_N + p0;
    {
        const int c = tid >> 4;            // 0..15
        const int p = (tid & 15) * 4;
        #pragma unroll
        for (int s = 0; s < 4; ++s) {
            const float4 t = *(const float4*)(xb + (size_t)(c + 16 * s) * HW_N + p);
            const float v[4] = { t.x, t.y, t.z, t.w };
            #pragma unroll
            for (int j = 0; j < 4; ++j) {
                const unsigned int hi = bf16_bits(v[j]);
                const float hif = __uint_as_float(hi << 16);
                const unsigned int lo = bf16_bits(v[j] - hif);
                Ls[c + 16 * s][p + j] = (hi << 16) | lo;
            }
        }
    }
    __syncthreads();
    unsigned int* xo = xt + ((size_t)b * HW_N + p0) * C_N + c0;
    {
        const int p = tid >> 4;
        const int c = (tid & 15) * 4;
        #pragma unroll
        for (int s = 0; s < 4; ++s) {
            uint4 r;
            r.x = Ls[c + 0][p + 16 * s];
            r.y = Ls[c + 1][p + 16 * s];
            r.z = Ls[c + 2][p + 16 * s];
            r.w = Ls[c + 3][p + 16 * s];
            *(uint4*)(xo + (size_t)(p + 16 * s) * C_N + c) = r;
        }
    }
}

// ---------------------------------------------------------------------------
// Kernel 1: QKV projection via bf16 MFMA with split-precision.
// Pipelined: raw s_barrier (no vmcnt drain) + prefetch distance 2 on the
// xt stream (two named reg sets, loop unrolled x2) and distance 1 on W
// (1.25 MB total -> L2-resident after first touch).
// ---------------------------------------------------------------------------
__global__ __launch_bounds__(256) void qkv_mfma_kernel(
    const unsigned int* __restrict__ xt,
    const float* __restrict__ wq, const float* __restrict__ bq,
    const float* __restrict__ wk, const float* __restrict__ bk,
    const float* __restrict__ wv, const float* __restrict__ bv,
    float* __restrict__ qk, unsigned short* __restrict__ vout)
{
    const int b    = blockIdx.z;
    const int by   = blockIdx.y;          // 0 = q+k, 1..4 = v
    const int p0   = blockIdx.x * 128;
    const int tid  = threadIdx.x;
    const bool qkblk = (by == 0);

    __shared__ __align__(16) unsigned short AsHi[128 * 64];
    __shared__ __align__(16) unsigned short AsLo[128 * 64];
    __shared__ __align__(16) unsigned short BsHi[128 * 64];
    __shared__ __align__(16) unsigned short BsLo[128 * 64];

    const int sq = tid & 7;               // 16B chunk within 64-wide K slab
    const int sr = tid >> 3;              // 0..31 (4 slabs of 32 rows)

    const int lane = tid & 63;
    const int wave = tid >> 6;
    const int wrow = (wave >> 1) * 64;    // m offset within tile
    const int wcol = (wave & 1) * 64;     // p offset within tile
    const int lrow = lane & 15;
    const int lk   = lane >> 4;

    const unsigned int* bt = xt + ((size_t)b * HW_N + p0) * C_N;  // [128 p][512 c]

    f32x4  acc[4][4] = {};
    float4 ra[4][2];                      // W staging (distance 1)
    uint4  rb0[4][2], rb1[4][2];          // xt staging (distance 2)

    auto wrowptr = [&](int r) -> const float* {
        if (qkblk) return (r < 64) ? (wq + (size_t)r * C_N)
                                   : (wk + (size_t)(r - 64) * C_N);
        return wv + (size_t)((by - 1) * 128 + r) * C_N;
    };

    auto loadW = [&](int k0) {
        #pragma unroll
        for (int s = 0; s < 4; ++s) {
            const float* pa = wrowptr(sr + 32 * s) + k0 + sq * 8;
            ra[s][0] = *(const float4*)(pa);
            ra[s][1] = *(const float4*)(pa + 4);
        }
    };
    auto loadX = [&](int k0, uint4 (&rb)[4][2]) {
        #pragma unroll
        for (int s = 0; s < 4; ++s) {
            const unsigned int* pb = bt + (size_t)(sr + 32 * s) * C_N + k0 + sq * 8;
            rb[s][0] = *(const uint4*)(pb);
            rb[s][1] = *(const uint4*)(pb + 4);
        }
    };

    auto write_tiles = [&](uint4 (&rb)[4][2]) {
        #pragma unroll
        for (int s = 0; s < 4; ++s) {
            const int r  = sr + 32 * s;
            const int ch = sq ^ (r & 7);
            const float e[8] = { ra[s][0].x, ra[s][0].y, ra[s][0].z, ra[s][0].w,
                                 ra[s][1].x, ra[s][1].y, ra[s][1].z, ra[s][1].w };
            unsigned int h[8];
            #pragma unroll
            for (int j = 0; j < 8; ++j) h[j] = bf16_bits(e[j]);
            uint4 ah;
            ah.x = h[0] | (h[1] << 16); ah.y = h[2] | (h[3] << 16);
            ah.z = h[4] | (h[5] << 16); ah.w = h[6] | (h[7] << 16);
            *reinterpret_cast<uint4*>(&AsHi[r * 64 + ch * 8]) = ah;
            if (qkblk) {
                unsigned int l[8];
                #pragma unroll
                for (int j = 0; j < 8; ++j) {
                    const float hf = __uint_as_float(h[j] << 16);
                    l[j] = bf16_bits(e[j] - hf);
                }
                uint4 al;
                al.x = l[0] | (l[1] << 16); al.y = l[2] | (l[3] << 16);
                al.z = l[4] | (l[5] << 16); al.w = l[6] | (l[7] << 16);
                *reinterpret_cast<uint4*>(&AsLo[r * 64 + ch * 8]) = al;
            }
            const unsigned int q0[8] = { rb[s][0].x, rb[s][0].y, rb[s][0].z, rb[s][0].w,
                                         rb[s][1].x, rb[s][1].y, rb[s][1].z, rb[s][1].w };
            uint4 bh, bl;
            bh.x = (q0[0] >> 16) | (q0[1] & 0xffff0000u);
            bh.y = (q0[2] >> 16) | (q0[3] & 0xffff0000u);
            bh.z = (q0[4] >> 16) | (q0[5] & 0xffff0000u);
            bh.w = (q0[6] >> 16) | (q0[7] & 0xffff0000u);
            bl.x = (q0[0] & 0xffffu) | (q0[1] << 16);
            bl.y = (q0[2] & 0xffffu) | (q0[3] << 16);
            bl.z = (q0[4] & 0xffffu) | (q0[5] << 16);
            bl.w = (q0[6] & 0xffffu) | (q0[7] << 16);
            *reinterpret_cast<uint4*>(&BsHi[r * 64 + ch * 8]) = bh;
            *reinterpret_cast<uint4*>(&BsLo[r * 64 + ch * 8]) = bl;
        }
    };

    auto compute = [&]() {
        #pragma unroll
        for (int kb = 0; kb < 2; ++kb) {
            bf16x8 bfh[4], bfl[4];
            #pragma unroll
            for (int n = 0; n < 4; ++n) {
                const int r  = wcol + n * 16 + lrow;
                const int ch = (kb * 4 + lk) ^ (lrow & 7);
                bfh[n] = *reinterpret_cast<const bf16x8*>(&BsHi[r * 64 + ch * 8]);
                bfl[n] = *reinterpret_cast<const bf16x8*>(&BsLo[r * 64 + ch * 8]);
            }
            #pragma unroll
            for (int m = 0; m < 4; ++m) {
                const int r  = wrow + m * 16 + lrow;
                const int ch = (kb * 4 + lk) ^ (lrow & 7);
                const bf16x8 ah = *reinterpret_cast<const bf16x8*>(&AsHi[r * 64 + ch * 8]);
                #pragma unroll
                for (int n = 0; n < 4; ++n) {
                    acc[m][n] = __builtin_amdgcn_mfma_f32_16x16x32_bf16(ah, bfh[n], acc[m][n], 0, 0, 0);
                    acc[m][n] = __builtin_amdgcn_mfma_f32_16x16x32_bf16(ah, bfl[n], acc[m][n], 0, 0, 0);
                }
                if (qkblk) {
                    const bf16x8 al = *reinterpret_cast<const bf16x8*>(&AsLo[r * 64 + ch * 8]);
                    #pragma unroll
                    for (int n = 0; n < 4; ++n)
                        acc[m][n] = __builtin_amdgcn_mfma_f32_16x16x32_bf16(al, bfh[n], acc[m][n], 0, 0, 0);
                }
            }
        }
    };

    loadX(0, rb0);
    loadX(64, rb1);
    loadW(0);
    for (int kt = 0; kt < 8; kt += 2) {
        // ---- tile kt (set 0) ----
        write_tiles(rb0);
        LGKM0();
        __builtin_amdgcn_s_barrier();
        if (kt + 2 < 8) loadX((kt + 2) * 64, rb0);
        loadW((kt + 1) * 64);                       // kt+1 <= 7 always
        compute();
        LGKM0();
        __builtin_amdgcn_s_barrier();
        // ---- tile kt+1 (set 1) ----
        write_tiles(rb1);
        LGKM0();
        __builtin_amdgcn_s_barrier();
        if (kt + 3 < 8) { loadX((kt + 3) * 64, rb1); loadW((kt + 2) * 64); }
        compute();
        LGKM0();
        __builtin_amdgcn_s_barrier();
    }

    #pragma unroll
    for (int m = 0; m < 4; ++m) {
        #pragma unroll
        for (int rr = 0; rr < 4; ++rr) {
            const int r = wrow + m * 16 + lk * 4 + rr;   // tile row 0..127
            if (qkblk) {
                const float bi = (r < 64) ? bq[r] : bk[r - 64];
                float* dst = qk + ((size_t)b * 128 + r) * HW_N + p0 + wcol + lrow;
                #pragma unroll
                for (int n = 0; n < 4; ++n)
                    dst[n * 16] = acc[m][n][rr] + bi;
            } else {
                const int vr = (by - 1) * 128 + r;
                const float bi = bv[vr];
                unsigned short* dst = vout + ((size_t)b * C_N + vr) * HW_N + p0 + wcol + lrow;
                #pragma unroll
                for (int n = 0; n < 4; ++n)
                    dst[n * 16] = (unsigned short)bf16_bits(acc[m][n][rr] + bi);
            }
        }
    }
}

// ---------------------------------------------------------------------------
// Kernel 1b: transpose + two-term bf16 split of the qk buffer.
// qk[b][m=0..127][p] fp32  ->  qkT[b][p][m] u32 = (hi<<16)|lo
// ---------------------------------------------------------------------------
__global__ __launch_bounds__(256) void qkt_transpose_kernel(
    const float* __restrict__ qk, unsigned int* __restrict__ qkT)
{
    const int b   = blockIdx.z;
    const int m0  = blockIdx.y * 64;       // 0 or 64
    const int p0  = blockIdx.x * 64;
    const int tid = threadIdx.x;

    __shared__ unsigned int Ls[64][65];

    const float* src = qk + ((size_t)b * 128 + m0) * HW_N + p0;
    {
        const int m = tid >> 4;
        const int p = (tid & 15) * 4;
        #pragma unroll
        for (int s = 0; s < 4; ++s) {
            const float4 t = *(const float4*)(src + (size_t)(m + 16 * s) * HW_N + p);
            const float v[4] = { t.x, t.y, t.z, t.w };
            #pragma unroll
            for (int j = 0; j < 4; ++j) {
                const unsigned int hi = bf16_bits(v[j]);
                const float hif = __uint_as_float(hi << 16);
                const unsigned int lo = bf16_bits(v[j] - hif);
                Ls[m + 16 * s][p + j] = (hi << 16) | lo;
            }
        }
    }
    __syncthreads();
    unsigned int* dst = qkT + ((size_t)b * HW_N + p0) * 128 + m0;
    {
        const int p = tid >> 4;
        const int m = (tid & 15) * 4;
        #pragma unroll
        for (int s = 0; s < 4; ++s) {
            uint4 r;
            r.x = Ls[m + 0][p + 16 * s];
            r.y = Ls[m + 1][p + 16 * s];
            r.z = Ls[m + 2][p + 16 * s];
            r.w = Ls[m + 3][p + 16 * s];
            *(uint4*)(dst + (size_t)(p + 16 * s) * 128 + m) = r;
        }
    }
}

// ---------------------------------------------------------------------------
// Kernel 2: energy via bf16 MFMA, 3-product split (fp32-grade).  Unchanged.
// ---------------------------------------------------------------------------
__global__ __launch_bounds__(256) void energy_mfma_kernel(
    const unsigned int* __restrict__ qkT, float* __restrict__ att)
{
    const int b   = blockIdx.z;
    const int i0  = blockIdx.y * 128;
    const int j0  = blockIdx.x * 128;
    const int tid = threadIdx.x;

    __shared__ __align__(16) unsigned short AsHi[128 * 64];
    __shared__ __align__(16) unsigned short AsLo[128 * 64];
    __shared__ __align__(16) unsigned short BsHi[128 * 64];
    __shared__ __align__(16) unsigned short BsLo[128 * 64];

    const int sq = tid & 7;
    const int sr = tid >> 3;

    const int lane = tid & 63;
    const int wave = tid >> 6;
    const int wrow = (wave >> 1) * 64;
    const int wcol = (wave & 1) * 64;
    const int lrow = lane & 15;
    const int lk   = lane >> 4;

    #pragma unroll
    for (int s = 0; s < 4; ++s) {
        const int r  = sr + 32 * s;
        const int ch = sq ^ (r & 7);
        {   // A: q channels of row i0+r
            const unsigned int* pa = qkT + ((size_t)b * HW_N + i0 + r) * 128 + sq * 8;
            const uint4 u0 = *(const uint4*)(pa);
            const uint4 u1 = *(const uint4*)(pa + 4);
            uint4 h, l;
            h.x = (u0.x >> 16) | (u0.y & 0xffff0000u);
            h.y = (u0.z >> 16) | (u0.w & 0xffff0000u);
            h.z = (u1.x >> 16) | (u1.y & 0xffff0000u);
            h.w = (u1.z >> 16) | (u1.w & 0xffff0000u);
            l.x = (u0.x & 0xffffu) | (u0.y << 16);
            l.y = (u0.z & 0xffffu) | (u0.w << 16);
            l.z = (u1.x & 0xffffu) | (u1.y << 16);
            l.w = (u1.z & 0xffffu) | (u1.w << 16);
            *reinterpret_cast<uint4*>(&AsHi[r * 64 + ch * 8]) = h;
            *reinterpret_cast<uint4*>(&AsLo[r * 64 + ch * 8]) = l;
        }
        {   // B: k channels of row j0+r
            const unsigned int* pb = qkT + ((size_t)b * HW_N + j0 + r) * 128 + 64 + sq * 8;
            const uint4 u0 = *(const uint4*)(pb);
            const uint4 u1 = *(const uint4*)(pb + 4);
            uint4 h, l;
            h.x = (u0.x >> 16) | (u0.y & 0xffff0000u);
            h.y = (u0.z >> 16) | (u0.w & 0xffff0000u);
            h.z = (u1.x >> 16) | (u1.y & 0xffff0000u);
            h.w = (u1.z >> 16) | (u1.w & 0xffff0000u);
            l.x = (u0.x & 0xffffu) | (u0.y << 16);
            l.y = (u0.z & 0xffffu) | (u0.w << 16);
            l.z = (u1.x & 0xffffu) | (u1.y << 16);
            l.w = (u1.z & 0xffffu) | (u1.w << 16);
            *reinterpret_cast<uint4*>(&BsHi[r * 64 + ch * 8]) = h;
            *reinterpret_cast<uint4*>(&BsLo[r * 64 + ch * 8]) = l;
        }
    }
    __syncthreads();

    f32x4 acc[4][4] = {};
    #pragma unroll
    for (int kb = 0; kb < 2; ++kb) {
        bf16x8 bfh[4], bfl[4];
        #pragma unroll
        for (int n = 0; n < 4; ++n) {
            const int r  = wcol + n * 16 + lrow;
            const int ch = (kb * 4 + lk) ^ (lrow & 7);
            bfh[n] = *reinterpret_cast<const bf16x8*>(&BsHi[r * 64 + ch * 8]);
            bfl[n] = *reinterpret_cast<const bf16x8*>(&BsLo[r * 64 + ch * 8]);
        }
        #pragma unroll
        for (int m = 0; m < 4; ++m) {
            const int r  = wrow + m * 16 + lrow;
            const int ch = (kb * 4 + lk) ^ (lrow & 7);
            const bf16x8 ah = *reinterpret_cast<const bf16x8*>(&AsHi[r * 64 + ch * 8]);
            const bf16x8 al = *reinterpret_cast<const bf16x8*>(&AsLo[r * 64 + ch * 8]);
            #pragma unroll
            for (int n = 0; n < 4; ++n) {
                acc[m][n] = __builtin_amdgcn_mfma_f32_16x16x32_bf16(ah, bfh[n], acc[m][n], 0, 0, 0);
                acc[m][n] = __builtin_amdgcn_mfma_f32_16x16x32_bf16(ah, bfl[n], acc[m][n], 0, 0, 0);
                acc[m][n] = __builtin_amdgcn_mfma_f32_16x16x32_bf16(al, bfh[n], acc[m][n], 0, 0, 0);
            }
        }
    }

    #pragma unroll
    for (int m = 0; m < 4; ++m) {
        #pragma unroll
        for (int rr = 0; rr < 4; ++rr) {
            const int i = i0 + wrow + m * 16 + lk * 4 + rr;
            float* dst = att + ((size_t)b * HW_N + i) * HW_N + j0 + wcol + lrow;
            #pragma unroll
            for (int n = 0; n < 4; ++n)
                dst[n * 16] = acc[m][n][rr];
        }
    }
}

// ---------------------------------------------------------------------------
// Kernel 3: row softmax in place (unchanged).
// ---------------------------------------------------------------------------
__global__ __launch_bounds__(256) void softmax_kernel(float* __restrict__ att)
{
    const size_t row = blockIdx.x;
    float* e = att + row * (size_t)HW_N;
    const int tid  = threadIdx.x;
    const int wv_  = tid >> 6;
    const int lane = tid & 63;

    float4 v = ((const float4*)e)[tid];

    float m = fmaxf(fmaxf(v.x, v.y), fmaxf(v.z, v.w));
    #pragma unroll
    for (int off = 32; off > 0; off >>= 1)
        m = fmaxf(m, __shfl_down(m, off, 64));
    __shared__ float red[4];
    if (lane == 0) red[wv_] = m;
    __syncthreads();
    m = fmaxf(fmaxf(red[0], red[1]), fmaxf(red[2], red[3]));
    __syncthreads();

    float4 ex;
    ex.x = __expf(v.x - m); ex.y = __expf(v.y - m);
    ex.z = __expf(v.z - m); ex.w = __expf(v.w - m);
    float s = ex.x + ex.y + ex.z + ex.w;
    #pragma unroll
    for (int off = 32; off > 0; off >>= 1)
        s += __shfl_down(s, off, 64);
    if (lane == 0) red[wv_] = s;
    __syncthreads();
    s = red[0] + red[1] + red[2] + red[3];

    const float inv = 1.0f / s;
    ex.x *= inv; ex.y *= inv; ex.z *= inv; ex.w *= inv;
    ((float4*)e)[tid] = ex;
}

// ---------------------------------------------------------------------------
// Kernel 4: out[b,c,i] = sum_j v[b,c,j] * att[b,i,j] via bf16 MFMA.
// Pipelined: raw s_barrier + prefetch distance 2 (two reg sets, loop x2).
// ---------------------------------------------------------------------------
__global__ __launch_bounds__(256) void out_kernel(
    const unsigned short* __restrict__ vout, const float* __restrict__ att,
    const float* __restrict__ x, const float* __restrict__ hha,
    const float* __restrict__ gamma,
    float* __restrict__ rgb, float* __restrict__ hho)
{
    const int b   = blockIdx.z;
    const int c0  = blockIdx.y * 128;
    const int i0  = blockIdx.x * 128;
    const int tid = threadIdx.x;

    const unsigned short* vptr = vout + (size_t)(b * C_N + c0) * HW_N;
    const float* aptr = att + (size_t)b * HW_N * HW_N + (size_t)i0 * HW_N;

    __shared__ __align__(16) unsigned short Vs[128 * 64];
    __shared__ __align__(16) unsigned short Ps[128 * 64];

    const int sq = tid & 7;
    const int sr = tid >> 3;

    const int lane = tid & 63;
    const int wave = tid >> 6;
    const int wrow = (wave >> 1) * 64;
    const int wcol = (wave & 1) * 64;
    const int lrow = lane & 15;
    const int lk   = lane >> 4;

    f32x4  acc[4][4] = {};
    uint4  ra0[4], ra1[4];          // v staging (bf16), two sets
    float4 rb0[4][2], rb1[4][2];    // att staging (fp32), two sets

    auto load_set = [&](int j0, uint4 (&ra)[4], float4 (&rb)[4][2]) {
        #pragma unroll
        for (int s = 0; s < 4; ++s) {
            ra[s] = *(const uint4*)(vptr + (size_t)(sr + 32 * s) * HW_N + j0 + sq * 8);
            const float* pb = aptr + (size_t)(sr + 32 * s) * HW_N + j0 + sq * 8;
            rb[s][0] = *(const float4*)(pb);
            rb[s][1] = *(const float4*)(pb + 4);
        }
    };

    auto write_set = [&](uint4 (&ra)[4], float4 (&rb)[4][2]) {
        #pragma unroll
        for (int s = 0; s < 4; ++s) {
            const int r  = sr + 32 * s;
            const int ch = sq ^ (r & 7);
            *reinterpret_cast<uint4*>(&Vs[r * 64 + ch * 8]) = ra[s];
            uint4 wb;
            wb.x = pack2_bf16(rb[s][0].x, rb[s][0].y);
            wb.y = pack2_bf16(rb[s][0].z, rb[s][0].w);
            wb.z = pack2_bf16(rb[s][1].x, rb[s][1].y);
            wb.w = pack2_bf16(rb[s][1].z, rb[s][1].w);
            *reinterpret_cast<uint4*>(&Ps[r * 64 + ch * 8]) = wb;
        }
    };

    auto compute = [&]() {
        #pragma unroll
        for (int kb = 0; kb < 2; ++kb) {
            bf16x8 af[4], bf[4];
            #pragma unroll
            for (int m = 0; m < 4; ++m) {
                const int r  = wrow + m * 16 + lrow;
                const int ch = (kb * 4 + lk) ^ (lrow & 7);
                af[m] = *reinterpret_cast<const bf16x8*>(&Vs[r * 64 + ch * 8]);
            }
            #pragma unroll
            for (int n = 0; n < 4; ++n) {
                const int r  = wcol + n * 16 + lrow;
                const int ch = (kb * 4 + lk) ^ (lrow & 7);
                bf[n] = *reinterpret_cast<const bf16x8*>(&Ps[r * 64 + ch * 8]);
            }
            #pragma unroll
            for (int m = 0; m < 4; ++m)
                #pragma unroll
                for (int n = 0; n < 4; ++n)
                    acc[m][n] = __builtin_amdgcn_mfma_f32_16x16x32_bf16(
                        af[m], bf[n], acc[m][n], 0, 0, 0);
        }
    };

    load_set(0, ra0, rb0);
    load_set(64, ra1, rb1);
    for (int jt = 0; jt < 16; jt += 2) {
        // ---- tile jt (set 0) ----
        write_set(ra0, rb0);
        LGKM0();
        __builtin_amdgcn_s_barrier();
        if (jt + 2 < 16) load_set((jt + 2) * 64, ra0, rb0);
        compute();
        LGKM0();
        __builtin_amdgcn_s_barrier();
        // ---- tile jt+1 (set 1) ----
        write_set(ra1, rb1);
        LGKM0();
        __builtin_amdgcn_s_barrier();
        if (jt + 3 < 16) load_set((jt + 3) * 64, ra1, rb1);
        compute();
        LGKM0();
        __builtin_amdgcn_s_barrier();
    }

    const float g    = gamma[0];
    const int   crow = c0 + wrow + lk * 4;
    const int   icol = i0 + wcol + lrow;
    #pragma unroll
    for (int m = 0; m < 4; ++m) {
        #pragma unroll
        for (int rr = 0; rr < 4; ++rr) {
            const int c = crow + m * 16 + rr;
            const size_t base = ((size_t)b * C_N + c) * HW_N + icol;
            #pragma unroll
            for (int n = 0; n < 4; ++n) {
                const float o  = acc[m][n][rr];
                const float xv = x[base + n * 16];
                const float hv = hha[base + n * 16];
                rgb[base + n * 16] = fmaf(g, o, xv);
                hho[base + n * 16] = fmaf(g, o, hv);
            }
        }
    }
}

// ---------------------------------------------------------------------------
extern "C" void kernel_launch(void* const* d_in, const int* in_sizes, int n_in,
                              void* d_out, int out_size, void* d_ws, size_t ws_size,
                              hipStream_t stream)
{
    const float* x     = (const float*)d_in[0];
    const float* hha   = (const float*)d_in[1];
    const float* wq    = (const float*)d_in[2];
    const float* bq    = (const float*)d_in[3];
    const float* wk    = (const float*)d_in[4];
    const float* bk    = (const float*)d_in[5];
    const float* wv    = (const float*)d_in[6];
    const float* bv    = (const float*)d_in[7];
    const float* gamma = (const float*)d_in[8];

    float* out = (float*)d_out;
    float* att = out;                                        // [32,1024,1024]
    float* rgb = att + (size_t)B_N * HW_N * HW_N;            // [32,512,1024]
    float* hho = rgb + (size_t)B_N * C_N * HW_N;             // [32,512,1024]

    // workspace layout:
    //   qkbuf  fp32 [32][128][1024]  = 16 MiB
    //   vbuf   bf16 [32][512][1024]  = 32 MiB
    //   qkT    u32  [32][1024][128]  = 16 MiB
    float*          qkbuf = (float*)d_ws;
    unsigned short* vbuf  = (unsigned short*)(qkbuf + (size_t)B_N * 128 * HW_N);
    unsigned int*   qkTb  = (unsigned int*)(vbuf + (size_t)B_N * C_N * HW_N);

    // xT split lives in the (not yet written) att region: 64 MiB of 128 MiB
    unsigned int* xt = (unsigned int*)att;

    xsplit_transpose_kernel<<<dim3(HW_N / 64, C_N / 64, B_N), 256, 0, stream>>>(x, xt);
    qkv_mfma_kernel<<<dim3(HW_N / 128, 5, B_N), 256, 0, stream>>>(
        xt, wq, bq, wk, bk, wv, bv, qkbuf, vbuf);
    qkt_transpose_kernel<<<dim3(HW_N / 64, 2, B_N), 256, 0, stream>>>(qkbuf, qkTb);
    energy_mfma_kernel<<<dim3(HW_N / 128, HW_N / 128, B_N), 256, 0, stream>>>(qkTb, att);
    softmax_kernel<<<dim3(B_N * HW_N), 256, 0, stream>>>(att);
    out_kernel<<<dim3(HW_N / 128, C_N / 128, B_N), 256, 0, stream>>>(
        vbuf, att, x, hha, gamma, rgb, hho);
}